// Round 1
// baseline (81.788 us; speedup 1.0000x reference)
//
#include <hip/hip_runtime.h>

// out[b,t,c] = x[b,t,c] + sum_{s=max(t-8,0)}^{t-1} isi[b,s,c]
// isi[..., f]    = h[f]*x[f]   - h[f+64]*x[f+64]   (f < 64)
// isi[..., f+64] = h[f]*x[f+64] + h[f+64]*x[f]
//
// B=32, T=8192, C=128, W=8. One wave per (b, 64-timestep chunk); lane f owns
// channel pair (f, f+64). Register ring buffer of the last 8 isi values,
// running window sums; inner loop unrolled by 8 so all ring indices are
// compile-time constants (stays in VGPRs, no scratch).

constexpr int TLEN  = 8192;
constexpr int CCH   = 128;
constexpr int FHALF = 64;
constexpr int WWIN  = 8;
constexpr int TC    = 64;            // timesteps per wave
constexpr int NCHUNK = TLEN / TC;    // 128
constexpr int NB    = 32;

__global__ __launch_bounds__(256) void isi_window_kernel(
    const float* __restrict__ x, const float* __restrict__ h,
    float* __restrict__ out)
{
    const int wave = threadIdx.x >> 6;
    const int lane = threadIdx.x & 63;
    const int gw   = blockIdx.x * 4 + wave;          // 0 .. NB*NCHUNK-1
    const int b     = gw >> 7;                       // gw / NCHUNK
    const int chunk = gw & (NCHUNK - 1);
    const int t0    = chunk * TC;

    const size_t base = (size_t)b * TLEN * CCH;
    const float* xb = x + base;
    const float* hb = h + base;
    float*       ob = out + base;

    float hist_r[WWIN], hist_i[WWIN];
    float win_r = 0.f, win_i = 0.f;
#pragma unroll
    for (int j = 0; j < WWIN; ++j) { hist_r[j] = 0.f; hist_i[j] = 0.f; }

    // Warm-up: the 8 timesteps before t0 (none for chunk 0; window starts empty).
    if (t0 > 0) {
        const int tw = t0 - WWIN;
#pragma unroll
        for (int j = 0; j < WWIN; ++j) {
            const size_t off = (size_t)(tw + j) * CCH + lane;
            const float xr = xb[off], xi = xb[off + FHALF];
            const float hr = hb[off], hi = hb[off + FHALF];
            const float ir = hr * xr - hi * xi;
            const float ii = hr * xi + hi * xr;
            hist_r[j] = ir; hist_i[j] = ii;
            win_r += ir;    win_i += ii;
        }
    }

    // Main: emit with current window, then slide window by one.
    for (int tb = t0; tb < t0 + TC; tb += WWIN) {
#pragma unroll
        for (int j = 0; j < WWIN; ++j) {
            const size_t off = (size_t)(tb + j) * CCH + lane;
            const float xr = xb[off], xi = xb[off + FHALF];
            const float hr = hb[off], hi = hb[off + FHALF];
            ob[off]         = xr + win_r;
            ob[off + FHALF] = xi + win_i;
            const float ir = hr * xr - hi * xi;
            const float ii = hr * xi + hi * xr;
            win_r += ir - hist_r[j];
            win_i += ii - hist_i[j];
            hist_r[j] = ir; hist_i[j] = ii;
        }
    }
}

extern "C" void kernel_launch(void* const* d_in, const int* in_sizes, int n_in,
                              void* d_out, int out_size, void* d_ws, size_t ws_size,
                              hipStream_t stream) {
    const float* x = (const float*)d_in[0];
    const float* h = (const float*)d_in[1];
    float* out = (float*)d_out;

    const int total_waves = NB * NCHUNK;             // 4096
    const int blocks = total_waves / 4;              // 1024 blocks of 4 waves
    isi_window_kernel<<<blocks, 256, 0, stream>>>(x, h, out);
}

// Round 3
// 70.482 us; speedup vs baseline: 1.1604x; 1.1604x over previous
//
#include <hip/hip_runtime.h>

// out[b,t,c] = x[b,t,c] + sum_{s=max(t-8,0)}^{t-1} isi[b,s,c]
// isi[..., f]    = h[f]*x[f]   - h[f+64]*x[f+64]   (f < 64)
// isi[..., f+64] = h[f]*x[f+64] + h[f+64]*x[f]
//
// B=32, T=8192, C=128, W=8.
// float2 version: each lane owns 2 adjacent channel pairs (2c,2c+64),(2c+1,2c+65),
// c = lane&31. Half-wave (32 lanes) covers one (b, chunk) column; a wave
// processes 2 adjacent chunks of the same batch. Register ring of last 8 isi
// values + running window sums, inner loop unrolled by 8 (compile-time ring
// indices -> VGPRs, no scratch). Nontemporal stores for the streamed output.
// Uses clang ext_vector_type (native vector) so nontemporal builtins accept it.

typedef float f2 __attribute__((ext_vector_type(2)));

constexpr int TLEN   = 8192;
constexpr int CCH    = 128;
constexpr int FHALF  = 64;
constexpr int WWIN   = 8;
constexpr int TC     = 32;            // timesteps per column-chunk
constexpr int NCHUNK = TLEN / TC;     // 256
constexpr int NB     = 32;

__global__ __launch_bounds__(256) void isi_window_kernel(
    const float* __restrict__ x, const float* __restrict__ h,
    float* __restrict__ out)
{
    const int wave = threadIdx.x >> 6;
    const int lane = threadIdx.x & 63;
    const int c2   = (lane & 31) * 2;                 // first channel of the pair-of-pairs
    const int half = lane >> 5;

    const int gw    = blockIdx.x * 4 + wave;          // 0 .. 4095
    const int col   = gw * 2 + half;                  // 0 .. 8191 (= b*NCHUNK + chunk)
    const int b     = col >> 8;                       // col / NCHUNK
    const int chunk = col & (NCHUNK - 1);
    const int t0    = chunk * TC;

    const size_t base = (size_t)b * TLEN * CCH + c2;
    const float* xb = x + base;
    const float* hb = h + base;
    float*       ob = out + base;

    f2 histr[WWIN], histi[WWIN];
    f2 winr = (f2)(0.f), wini = (f2)(0.f);
#pragma unroll
    for (int j = 0; j < WWIN; ++j) {
        histr[j] = (f2)(0.f);
        histi[j] = (f2)(0.f);
    }

    // Warm-up: the 8 timesteps before t0 (chunk 0 starts with an empty window).
    if (t0 > 0) {
        const int tw = t0 - WWIN;
#pragma unroll
        for (int j = 0; j < WWIN; ++j) {
            const size_t off = (size_t)(tw + j) * CCH;
            const f2 xr = *(const f2*)(xb + off);
            const f2 xi = *(const f2*)(xb + off + FHALF);
            const f2 hr = *(const f2*)(hb + off);
            const f2 hi = *(const f2*)(hb + off + FHALF);
            const f2 ir = hr * xr - hi * xi;
            const f2 ii = hr * xi + hi * xr;
            histr[j] = ir; histi[j] = ii;
            winr += ir; wini += ii;
        }
    }

    // Main loop: emit with current window, then slide by one.
    for (int tb = t0; tb < t0 + TC; tb += WWIN) {
#pragma unroll
        for (int j = 0; j < WWIN; ++j) {
            const size_t off = (size_t)(tb + j) * CCH;
            const f2 xr = *(const f2*)(xb + off);
            const f2 xi = *(const f2*)(xb + off + FHALF);
            const f2 hr = *(const f2*)(hb + off);
            const f2 hi = *(const f2*)(hb + off + FHALF);

            const f2 o0 = xr + winr;
            const f2 o1 = xi + wini;
            __builtin_nontemporal_store(o0, (f2*)(ob + off));
            __builtin_nontemporal_store(o1, (f2*)(ob + off + FHALF));

            const f2 ir = hr * xr - hi * xi;
            const f2 ii = hr * xi + hi * xr;

            winr += ir - histr[j];
            wini += ii - histi[j];
            histr[j] = ir; histi[j] = ii;
        }
    }
}

extern "C" void kernel_launch(void* const* d_in, const int* in_sizes, int n_in,
                              void* d_out, int out_size, void* d_ws, size_t ws_size,
                              hipStream_t stream) {
    const float* x = (const float*)d_in[0];
    const float* h = (const float*)d_in[1];
    float* out = (float*)d_out;

    const int total_cols  = NB * NCHUNK;              // 8192 columns
    const int total_waves = total_cols / 2;           // 4096 (2 columns per wave)
    const int blocks      = total_waves / 4;          // 1024 blocks of 4 waves
    isi_window_kernel<<<blocks, 256, 0, stream>>>(x, h, out);
}